// Round 8
// baseline (75.842 us; speedup 1.0000x reference)
//
#include <hip/hip_runtime.h>

typedef __bf16 bf16x8 __attribute__((ext_vector_type(8)));
typedef float  f32x4  __attribute__((ext_vector_type(4)));
typedef unsigned short ushort_t;

#define B_TOTAL 65536
#define NSTILE  4096   // B_TOTAL / 16 sample-tiles

// ---------------- helpers ----------------------------------------------------
__device__ __forceinline__ ushort_t f2bf(float f) {
  unsigned u = __builtin_bit_cast(unsigned, f);
  u += 0x7fffu + ((u >> 16) & 1u);          // RNE
  return (ushort_t)(u >> 16);
}
__device__ __forceinline__ unsigned pk2(float lo, float hi) {
  unsigned r;
  asm("v_cvt_pk_bf16_f32 %0, %1, %2" : "=v"(r) : "v"(lo), "v"(hi));
  return r;
}
__device__ __forceinline__ float lrelu(float v) { return v >= 0.f ? v : 0.1f * v; }
// swizzled ushort index into a row-major bf16 LDS tile (rb = row stride bytes, mult of 128)
__device__ __forceinline__ int swzi(int row, int rb, int col) {
  return ((row * rb + col * 2) ^ ((row & 7) << 4)) >> 1;
}
__device__ __forceinline__ bf16x8 ld_frag(const ushort_t* p8) {
  return __builtin_bit_cast(bf16x8, *(const uint4*)p8);
}
__device__ __forceinline__ bf16x8 frag_swz(const ushort_t* base, int row, int rb, int kcol0) {
  int b = (row * rb + kcol0 * 2) ^ ((row & 7) << 4);
  return __builtin_bit_cast(bf16x8, *(const uint4*)((const char*)base + b));
}
__device__ __forceinline__ f32x4 mfma16(bf16x8 a, bf16x8 b, f32x4 c) {
  return __builtin_amdgcn_mfma_f32_16x16x32_bf16(a, b, c, 0, 0, 0);
}

// ---------------- BatchNorm stats --------------------------------------------
__global__ __launch_bounds__(256) void bn_partial(const float* __restrict__ xc,
                                                  float* __restrict__ ws) {
  __shared__ float red[512];
  const int t = threadIdx.x;
  const int c = t & 15, g = t >> 4;
  const int r0 = blockIdx.x * 256;
  float s = 0.f, q = 0.f;
  for (int i = 0; i < 16; ++i) {
    float v = xc[(size_t)(r0 + g + i * 16) * 16 + c];
    s += v; q += v * v;
  }
  red[t] = s; red[256 + t] = q;
  __syncthreads();
  if (t < 16) {
    float ss = 0.f, qq = 0.f;
    for (int gg = 0; gg < 16; ++gg) { ss += red[gg * 16 + t]; qq += red[256 + gg * 16 + t]; }
    ws[blockIdx.x * 32 + t] = ss;
    ws[blockIdx.x * 32 + 16 + t] = qq;
  }
}

__global__ __launch_bounds__(256) void bn_final(const float* __restrict__ ws_in,
                                                float* __restrict__ ws_out,
                                                const float* __restrict__ g_,
                                                const float* __restrict__ b_) {
  __shared__ float red[512];
  const int t = threadIdx.x;
  const int c = t & 15, g = t >> 4;
  float s = 0.f, q = 0.f;
  for (int i = 0; i < 16; ++i) {
    int blk = g * 16 + i;
    s += ws_in[blk * 32 + c];
    q += ws_in[blk * 32 + 16 + c];
  }
  red[t] = s; red[256 + t] = q;
  __syncthreads();
  if (t < 16) {
    float ss = 0.f, qq = 0.f;
    for (int gg = 0; gg < 16; ++gg) { ss += red[gg * 16 + t]; qq += red[256 + gg * 16 + t]; }
    float mean  = ss / (float)B_TOTAL;
    float var   = qq / (float)B_TOTAL - mean * mean;
    float scale = g_[t] / sqrtf(var + 1e-5f);
    ws_out[8192 + t]      = scale;
    ws_out[8192 + 16 + t] = b_[t] - mean * scale;
  }
}

// ---------------- Weight packing: f32 -> bf16 in MFMA fragment order ---------
__global__ __launch_bounds__(256) void pack_weights(const float* __restrict__ W1,
                                                    const float* __restrict__ W2,
                                                    const float* __restrict__ Wl,
                                                    ushort_t* __restrict__ w1p,
                                                    ushort_t* __restrict__ w2p,
                                                    ushort_t* __restrict__ wlp) {
  int u = blockIdx.x * 256 + threadIdx.x;
  if (u < 32768) {                                 // W1: K 48->64, N 512 (NT=32, KB=2)
    int i = u & 7, lane = (u >> 3) & 63, kb = u >> 14;
    int k = kb * 32 + ((lane >> 4) << 3) + i;
    int n = (((u >> 9) & 31) << 4) + (lane & 15);
    w1p[u] = f2bf(k < 48 ? W1[k * 512 + n] : 0.f);
  } else if (u < 32768 + 131072) {                 // W2: K 512, N 256 (NT=16, KB=16)
    int v = u - 32768;
    int i = v & 7, lane = (v >> 3) & 63, kb = v >> 13;
    int k = kb * 32 + ((lane >> 4) << 3) + i;
    int n = (((v >> 9) & 15) << 4) + (lane & 15);
    w2p[v] = f2bf(W2[k * 256 + n]);
  } else if (u < 32768 + 131072 + 12288) {         // Wlin: K 384 (ffc 0..107 pad->128 | h2 128..383), N 24->32
    int v = u - (32768 + 131072);
    int i = v & 7, lane = (v >> 3) & 63, kb = v >> 10;
    int k = kb * 32 + ((lane >> 4) << 3) + i;
    int n = (((v >> 9) & 1) << 4) + (lane & 15);
    float val = 0.f;
    if (n < 24) {
      if (k < 108)       val = Wl[k * 24 + n];
      else if (k >= 128) val = Wl[(k - 20) * 24 + n];
    }
    wlp[v] = f2bf(val);
  }
}

// ---------------- Conv-as-GEMM weight matrices -------------------------------
struct WkPtrs { const float* wk[12]; };

__global__ __launch_bounds__(256) void pack_conv(WkPtrs wp,
                                                 ushort_t* __restrict__ Apack,
                                                 ushort_t* __restrict__ Bpack) {
  int u = blockIdx.x * 256 + threadIdx.x;
  if (u < 20480) {
    int i = u & 7, lane = (u >> 3) & 63;
    int knt = u >> 9;                  // kb*5 + nt
    int kb = knt / 5, nt = knt % 5;
    int k = kb * 32 + ((lane >> 4) << 3) + i;
    int n = nt * 16 + (lane & 15);
    float val = 0.f;
    if (n < 72 && k < 240) {
      int br = n / 12, ii = n - br * 12, ks = br + 1, lin = 240 - br;
      int si = ii * lin / 12, ei = ((ii + 1) * lin + 11) / 12;
      const float* wa = wp.wk[2 * br];
      float acc = 0.f;
      for (int kk = 0; kk < ks; ++kk) {
        int j = k - kk;
        if (j >= si && j < ei) acc += wa[kk];
      }
      val = acc / (float)(ei - si);
    }
    Apack[u] = f2bf(val);
  } else if (u < 20480 + 6144) {
    int v = u - 20480;
    int i = v & 7, lane = (v >> 3) & 63;
    int knt = v >> 9;                  // kb*3 + nt
    int kb = knt / 3, nt = knt % 3;
    int kcol = kb * 32 + ((lane >> 4) << 3) + i;
    int n = nt * 16 + (lane & 15);
    float val = 0.f;
    if (n < 36 && kcol < 108) {
      int brk = kcol / 18, ii = kcol - brk * 18;
      int brn = n / 6, j = n - brn * 6;
      if (brk == brn && ii < 12) {
        int ks = brn + 1, lcb = 12 - 2 * brn;
        int sj = j * lcb / 6, ej = ((j + 1) * lcb + 5) / 6;
        const float* wb = wp.wk[2 * brn + 1];
        float acc = 0.f;
        for (int kk = 0; kk < ks; ++kk) {
          int q = ii - 2 * kk;
          if (q >= sj && q < ej) acc += wb[kk];
        }
        val = acc / (float)(ej - sj);
      }
    }
    Bpack[v] = f2bf(val);
  }
}

// ---------------- Conv kernel: all-MFMA, 64 samples / block ------------------
struct ConvParams {
  const float* xw;
  const ushort_t* Apack;
  const ushort_t* Bpack;
  ushort_t*    ffc;        // packed B-frag order: ((kb*NSTILE + stile)*64 + lane)*8 + i
};

__global__ __launch_bounds__(512, 6) void conv_kernel(ConvParams p) {
  // LDS 48 KB -> 3 blocks/CU
  __shared__ __align__(16) char smem[49152];
  ushort_t* s_xw = (ushort_t*)smem;            // [64][256] bf16 swz rb=512
  ushort_t* s_fc = (ushort_t*)(smem + 32768);  // [64][128] bf16 swz rb=256

  const int t = threadIdx.x, lane = t & 63, w = t >> 6;
  const int s0 = blockIdx.x * 64;
  const f32x4 fzero = {0.f, 0.f, 0.f, 0.f};

  for (int u = t; u < 1024; u += 512) ((uint4*)s_fc)[u] = uint4{0, 0, 0, 0};
  if (t < 128) {
    int r = t >> 1, m = t & 1;
    *(uint4*)((char*)s_xw + ((r * 512 + 480 + m * 16) ^ ((r & 7) << 4))) = uint4{0, 0, 0, 0};
  }
  for (int u = t; u < 64 * 60; u += 512) {
    int s = u / 60, m4 = u - s * 60;
    float4 v = *(const float4*)(p.xw + (size_t)(s0 + s) * 240 + 4 * m4);
    uint2 pkv; pkv.x = pk2(v.x, v.y); pkv.y = pk2(v.z, v.w);
    *(uint2*)((char*)s_xw + ((s * 512 + m4 * 8) ^ ((s & 7) << 4))) = pkv;
  }
  __syncthreads();

  // GEMM0a: FA[72 n][64 samp] = leaky(xw @ A); scatter to s_fc cols n+6*br
  auto do0a = [&](int nt, int st) {
    f32x4 acc = fzero;
    #pragma unroll
    for (int kb = 0; kb < 8; ++kb) {
      bf16x8 a = ld_frag(p.Apack + (size_t)((kb * 5 + nt) * 64 + lane) * 8);
      bf16x8 b = frag_swz(s_xw, st * 16 + (lane & 15), 512, kb * 32 + ((lane >> 4) << 3));
      acc = mfma16(a, b, acc);
    }
    int n0 = nt * 16 + ((lane >> 4) << 2);
    int br = n0 / 12;
    int col0 = n0 + 6 * br;
    int row = st * 16 + (lane & 15);
    unsigned lo = pk2(lrelu(acc[0]), lrelu(acc[1]));
    unsigned hi = pk2(lrelu(acc[2]), lrelu(acc[3]));
    *(unsigned*)((char*)s_fc + ((row * 256 + col0 * 2) ^ ((row & 7) << 4))) = lo;
    *(unsigned*)((char*)s_fc + ((row * 256 + (col0 + 2) * 2) ^ ((row & 7) << 4))) = hi;
  };
  do0a(w % 5, w / 5);
  do0a((w + 8) % 5, (w + 8) / 5);
  if (w < 4) do0a((w + 16) % 5, (w + 16) / 5);
  __syncthreads();

  // GEMM0b: FB[36 n][64 samp] = leaky(fa @ Bblk)
  const int nt0 = w % 3, st0 = w / 3;
  f32x4 accB0 = fzero, accB1 = fzero;
  #pragma unroll
  for (int kb = 0; kb < 4; ++kb) {
    bf16x8 a = ld_frag(p.Bpack + (size_t)((kb * 3 + nt0) * 64 + lane) * 8);
    bf16x8 b = frag_swz(s_fc, st0 * 16 + (lane & 15), 256, kb * 32 + ((lane >> 4) << 3));
    accB0 = mfma16(a, b, accB0);
  }
  const int nt1 = (w + 8) % 3, st1 = (w + 8) / 3;
  if (w < 4) {
    #pragma unroll
    for (int kb = 0; kb < 4; ++kb) {
      bf16x8 a = ld_frag(p.Bpack + (size_t)((kb * 3 + nt1) * 64 + lane) * 8);
      bf16x8 b = frag_swz(s_fc, st1 * 16 + (lane & 15), 256, kb * 32 + ((lane >> 4) << 3));
      accB1 = mfma16(a, b, accB1);
    }
  }
  __syncthreads();
  auto wr0b = [&](f32x4 acc, int nt, int st) {
    int n0 = nt * 16 + ((lane >> 4) << 2);
    if (n0 < 36) {
      int row = st * 16 + (lane & 15);
      int br0 = n0 / 6, c0 = n0 + 12 * (br0 + 1);
      int n2 = n0 + 2, br2 = n2 / 6, c2 = n2 + 12 * (br2 + 1);
      *(unsigned*)((char*)s_fc + ((row * 256 + c0 * 2) ^ ((row & 7) << 4))) =
          pk2(lrelu(acc[0]), lrelu(acc[1]));
      *(unsigned*)((char*)s_fc + ((row * 256 + c2 * 2) ^ ((row & 7) << 4))) =
          pk2(lrelu(acc[2]), lrelu(acc[3]));
    }
  };
  wr0b(accB0, nt0, st0);
  if (w < 4) wr0b(accB1, nt1, st1);
  __syncthreads();

  // pack ffc to global in GEMM3 B-frag order (kb 0..3 = cols 0..127)
  for (int u = t; u < 1024; u += 512) {
    int ln = u & 63, st = (u >> 6) & 3, kb = u >> 8;
    int row = st * 16 + (ln & 15);
    int colb = (kb * 32 + ((ln >> 4) << 3)) * 2;
    uint4 v = *(const uint4*)((const char*)s_fc + ((row * 256 + colb) ^ ((row & 7) << 4)));
    size_t stile = (size_t)blockIdx.x * 4 + st;
    *(uint4*)((char*)p.ffc + (((size_t)kb * NSTILE + stile) * 64 + ln) * 16) = v;
  }
}

// ---------------- MLP kernel: 32 samples / block, 36 KB LDS, high occupancy --
struct MlpParams {
  const int*   xcat;
  const float* xcont;
  const float* E0; const float* E1; const float* E2;
  const float* b1; const float* b2;
  const ushort_t* w1p; const ushort_t* w2p; const ushort_t* wlp;
  const ushort_t* ffc;
  const float* stats;
  float*       out;
};

__global__ __launch_bounds__(512, 6) void mlp_kernel(MlpParams p) {
  // LDS 36992 B -> up to 4 blocks/CU (LDS); 3-4 by VGPR
  //   [0,32768)       s_h1 bf16[32][512] swz rb=1024 ; after GEMM2: s_fc bf16[32][256] swz rb=512
  //   [32768,36864)   s_x48 bf16[32][64] swz rb=128
  __shared__ __align__(16) char smem[36992];
  ushort_t* s_h1  = (ushort_t*)smem;
  ushort_t* s_fc  = (ushort_t*)smem;
  ushort_t* s_x48 = (ushort_t*)(smem + 32768);

  const int t    = threadIdx.x;
  const int lane = t & 63;
  const int w    = t >> 6;
  const int s0   = blockIdx.x * 32;
  const f32x4 fzero = {0.f, 0.f, 0.f, 0.f};

  // W2 prologue prefetch: depth 2 (kb 0,1) — issued before any barrier
  const int nt2 = w * 2;
  uint4 pa[2][2];
  #pragma unroll
  for (int q = 0; q < 2; ++q) {
    pa[q][0] = *(const uint4*)(p.w2p + (size_t)((q * 16 + nt2 + 0) * 64 + lane) * 8);
    pa[q][1] = *(const uint4*)(p.w2p + (size_t)((q * 16 + nt2 + 1) * 64 + lane) * 8);
  }

  // x48 = [emb | bn(xcont)] ; pad cols 48..63 zero
  for (int u = t; u < 32 * 16; u += 512) { int s = u >> 4; s_x48[swzi(s, 128, 48 + (u & 15))] = 0; }
  for (int u = t; u < 32 * 48; u += 512) {
    int s = u / 48, c = u - s * 48, gs = s0 + s;
    float v;
    if (c < 20)      v = p.E0[(size_t)p.xcat[gs * 3 + 0] * 20 + c];
    else if (c < 24) v = p.E1[(size_t)p.xcat[gs * 3 + 1] * 4 + (c - 20)];
    else if (c < 32) v = p.E2[(size_t)p.xcat[gs * 3 + 2] * 8 + (c - 24)];
    else { int cc = c - 32; v = p.xcont[(size_t)gs * 16 + cc] * p.stats[cc] + p.stats[16 + cc]; }
    s_x48[swzi(s, 128, c)] = f2bf(v);
  }
  __syncthreads();

  // --- GEMM1: h1[n][samp] = relu(x48 @ W1 + b1); wave w: nt = 4w..4w+3, st 0..1
  {
    bf16x8 bx[2][2];
    #pragma unroll
    for (int st = 0; st < 2; ++st)
      #pragma unroll
      for (int kb = 0; kb < 2; ++kb)
        bx[st][kb] = frag_swz(s_x48, st * 16 + (lane & 15), 128, kb * 32 + ((lane >> 4) << 3));
    #pragma unroll
    for (int j = 0; j < 4; ++j) {
      int nt = w * 4 + j;
      bf16x8 a0 = ld_frag(p.w1p + (size_t)((0 * 32 + nt) * 64 + lane) * 8);
      bf16x8 a1 = ld_frag(p.w1p + (size_t)((1 * 32 + nt) * 64 + lane) * 8);
      f32x4 acc[2];
      #pragma unroll
      for (int st = 0; st < 2; ++st) {
        acc[st] = mfma16(a0, bx[st][0], fzero);
        acc[st] = mfma16(a1, bx[st][1], acc[st]);
      }
      int n0 = nt * 16 + ((lane >> 4) << 2);
      float4 bb = *(const float4*)(p.b1 + n0);
      #pragma unroll
      for (int st = 0; st < 2; ++st) {
        int row = st * 16 + (lane & 15);
        float v0 = fmaxf(acc[st][0] + bb.x, 0.f);
        float v1 = fmaxf(acc[st][1] + bb.y, 0.f);
        float v2 = fmaxf(acc[st][2] + bb.z, 0.f);
        float v3 = fmaxf(acc[st][3] + bb.w, 0.f);
        uint2 pkv; pkv.x = pk2(v0, v1); pkv.y = pk2(v2, v3);
        *(uint2*)((char*)s_h1 + ((row * 1024 + n0 * 2) ^ ((row & 7) << 4))) = pkv;
      }
    }
  }
  __syncthreads();

  // hoist ffc B-frags (consumed by GEMM3) — latency hidden under GEMM2
  uint4 fbf[4];
  if (w < 4) {
    const int st3 = w & 1;
    const size_t stile = (size_t)blockIdx.x * 2 + st3;
    #pragma unroll
    for (int kb = 0; kb < 4; ++kb)
      fbf[kb] = *(const uint4*)((const char*)p.ffc +
                  (((size_t)kb * NSTILE + stile) * 64 + lane) * 16);
  }

  // --- GEMM2: h2 = relu(h1 @ W2 + b2); wave w: nt = 2w, 2w+1; st 0..1; depth-2
  f32x4 acc2[2][2];
  #pragma unroll
  for (int jm = 0; jm < 2; ++jm) { acc2[jm][0] = fzero; acc2[jm][1] = fzero; }
  #pragma unroll
  for (int kb = 0; kb < 16; ++kb) {
    bf16x8 a0 = __builtin_bit_cast(bf16x8, pa[kb & 1][0]);
    bf16x8 a1 = __builtin_bit_cast(bf16x8, pa[kb & 1][1]);
    if (kb < 14) {
      pa[kb & 1][0] = *(const uint4*)(p.w2p + (size_t)(((kb + 2) * 16 + nt2 + 0) * 64 + lane) * 8);
      pa[kb & 1][1] = *(const uint4*)(p.w2p + (size_t)(((kb + 2) * 16 + nt2 + 1) * 64 + lane) * 8);
    }
    #pragma unroll
    for (int st = 0; st < 2; ++st) {
      bf16x8 b = frag_swz(s_h1, st * 16 + (lane & 15), 1024, kb * 32 + ((lane >> 4) << 3));
      acc2[0][st] = mfma16(a0, b, acc2[0][st]);
      acc2[1][st] = mfma16(a1, b, acc2[1][st]);
    }
  }
  __syncthreads();   // all h1 reads complete before overlaying region with h2

  // --- h2 epilogue -> s_fc [32][256] rb=512
  #pragma unroll
  for (int jm = 0; jm < 2; ++jm) {
    int n0 = (nt2 + jm) * 16 + ((lane >> 4) << 2);
    float4 bb = *(const float4*)(p.b2 + n0);
    #pragma unroll
    for (int st = 0; st < 2; ++st) {
      int row = st * 16 + (lane & 15);
      float v0 = fmaxf(acc2[jm][st][0] + bb.x, 0.f);
      float v1 = fmaxf(acc2[jm][st][1] + bb.y, 0.f);
      float v2 = fmaxf(acc2[jm][st][2] + bb.z, 0.f);
      float v3 = fmaxf(acc2[jm][st][3] + bb.w, 0.f);
      uint2 pkv; pkv.x = pk2(v0, v1); pkv.y = pk2(v2, v3);
      *(uint2*)((char*)s_fc + ((row * 512 + n0 * 2) ^ ((row & 7) << 4))) = pkv;
    }
  }
  __syncthreads();

  // --- GEMM3: out[32][24] = [ffc(pad128) | h2] @ Wlin ; waves 0-3: st = w&1, nt = w>>1
  if (w < 4) {
    const int st = w & 1, nt = w >> 1;
    f32x4 acc = fzero;
    #pragma unroll
    for (int kb = 0; kb < 12; ++kb) {
      bf16x8 a = ld_frag(p.wlp + (size_t)((kb * 2 + nt) * 64 + lane) * 8);
      bf16x8 b;
      if (kb < 4) b = __builtin_bit_cast(bf16x8, fbf[kb]);
      else        b = frag_swz(s_fc, st * 16 + (lane & 15), 512, (kb - 4) * 32 + ((lane >> 4) << 3));
      acc = mfma16(a, b, acc);
    }
    int n0 = nt * 16 + ((lane >> 4) << 2);
    if (n0 < 24) {
      int sg = s0 + st * 16 + (lane & 15);
      *(float2*)(p.out + (size_t)sg * 24 + n0)     = make_float2(acc[0], acc[1]);
      *(float2*)(p.out + (size_t)sg * 24 + n0 + 2) = make_float2(acc[2], acc[3]);
    }
  }
}

// ---------------- launch -----------------------------------------------------
extern "C" void kernel_launch(void* const* d_in, const int* in_sizes, int n_in,
                              void* d_out, int out_size, void* d_ws, size_t ws_size,
                              hipStream_t stream) {
  const float* xcont = (const float*)d_in[2];
  float* ws  = (float*)d_ws;
  char*  wsb = (char*)d_ws;
  ushort_t* w1p   = (ushort_t*)(wsb + 36864);    //  64 KB
  ushort_t* w2p   = (ushort_t*)(wsb + 102400);   // 256 KB
  ushort_t* wlp   = (ushort_t*)(wsb + 364544);   //  24 KB
  ushort_t* Apack = (ushort_t*)(wsb + 389120);   //  40 KB
  ushort_t* Bpack = (ushort_t*)(wsb + 430080);   //  12 KB
  ushort_t* ffc   = (ushort_t*)(wsb + 524288);   //  16.78 MB

  // all prep first (conv depends only on pack_conv; mlp on the rest)
  WkPtrs wp;
  for (int i = 0; i < 12; ++i) wp.wk[i] = (const float*)d_in[3 + i];
  pack_conv<<<104, 256, 0, stream>>>(wp, Apack, Bpack);
  bn_partial<<<256, 256, 0, stream>>>(xcont, ws);
  bn_final<<<1, 256, 0, stream>>>(ws, ws, (const float*)d_in[18], (const float*)d_in[19]);
  pack_weights<<<688, 256, 0, stream>>>((const float*)d_in[20], (const float*)d_in[22],
                                        (const float*)d_in[24], w1p, w2p, wlp);

  ConvParams cp;
  cp.xw = (const float*)d_in[0];
  cp.Apack = Apack; cp.Bpack = Bpack;
  cp.ffc = ffc;
  conv_kernel<<<B_TOTAL / 64, 512, 0, stream>>>(cp);

  MlpParams p;
  p.xcat  = (const int*)d_in[1];
  p.xcont = xcont;
  p.E0 = (const float*)d_in[15]; p.E1 = (const float*)d_in[16]; p.E2 = (const float*)d_in[17];
  p.b1 = (const float*)d_in[21]; p.b2 = (const float*)d_in[23];
  p.w1p = w1p; p.w2p = w2p; p.wlp = wlp; p.ffc = ffc;
  p.stats = ws + 8192;
  p.out = (float*)d_out;
  mlp_kernel<<<B_TOTAL / 32, 512, 0, stream>>>(p);
}

// Round 9
// 68.104 us; speedup vs baseline: 1.1136x; 1.1136x over previous
//
#include <hip/hip_runtime.h>

typedef __bf16 bf16x8 __attribute__((ext_vector_type(8)));
typedef float  f32x4  __attribute__((ext_vector_type(4)));
typedef unsigned short ushort_t;

#define B_TOTAL 65536

// ---------------- helpers ----------------------------------------------------
__device__ __forceinline__ ushort_t f2bf(float f) {
  unsigned u = __builtin_bit_cast(unsigned, f);
  u += 0x7fffu + ((u >> 16) & 1u);          // RNE
  return (ushort_t)(u >> 16);
}
__device__ __forceinline__ unsigned pk2(float lo, float hi) {
  unsigned r;
  asm("v_cvt_pk_bf16_f32 %0, %1, %2" : "=v"(r) : "v"(lo), "v"(hi));
  return r;
}
__device__ __forceinline__ float lrelu(float v) { return v >= 0.f ? v : 0.1f * v; }
// swizzled ushort index into a row-major bf16 LDS tile (rb = row stride bytes, mult of 128)
__device__ __forceinline__ int swzi(int row, int rb, int col) {
  return ((row * rb + col * 2) ^ ((row & 7) << 4)) >> 1;
}
__device__ __forceinline__ bf16x8 ld_frag(const ushort_t* p8) {
  return __builtin_bit_cast(bf16x8, *(const uint4*)p8);
}
__device__ __forceinline__ bf16x8 frag_swz(const ushort_t* base, int row, int rb, int kcol0) {
  int b = (row * rb + kcol0 * 2) ^ ((row & 7) << 4);
  return __builtin_bit_cast(bf16x8, *(const uint4*)((const char*)base + b));
}
__device__ __forceinline__ f32x4 mfma16(bf16x8 a, bf16x8 b, f32x4 c) {
  return __builtin_amdgcn_mfma_f32_16x16x32_bf16(a, b, c, 0, 0, 0);
}

// ---------------- BatchNorm stats --------------------------------------------
__global__ __launch_bounds__(256) void bn_partial(const float* __restrict__ xc,
                                                  float* __restrict__ ws) {
  __shared__ float red[512];
  const int t = threadIdx.x;
  const int c = t & 15, g = t >> 4;
  const int r0 = blockIdx.x * 256;
  float s = 0.f, q = 0.f;
  for (int i = 0; i < 16; ++i) {
    float v = xc[(size_t)(r0 + g + i * 16) * 16 + c];
    s += v; q += v * v;
  }
  red[t] = s; red[256 + t] = q;
  __syncthreads();
  if (t < 16) {
    float ss = 0.f, qq = 0.f;
    for (int gg = 0; gg < 16; ++gg) { ss += red[gg * 16 + t]; qq += red[256 + gg * 16 + t]; }
    ws[blockIdx.x * 32 + t] = ss;
    ws[blockIdx.x * 32 + 16 + t] = qq;
  }
}

__global__ __launch_bounds__(256) void bn_final(const float* __restrict__ ws_in,
                                                float* __restrict__ ws_out,
                                                const float* __restrict__ g_,
                                                const float* __restrict__ b_) {
  __shared__ float red[512];
  const int t = threadIdx.x;
  const int c = t & 15, g = t >> 4;
  float s = 0.f, q = 0.f;
  for (int i = 0; i < 16; ++i) {
    int blk = g * 16 + i;
    s += ws_in[blk * 32 + c];
    q += ws_in[blk * 32 + 16 + c];
  }
  red[t] = s; red[256 + t] = q;
  __syncthreads();
  if (t < 16) {
    float ss = 0.f, qq = 0.f;
    for (int gg = 0; gg < 16; ++gg) { ss += red[gg * 16 + t]; qq += red[256 + gg * 16 + t]; }
    float mean  = ss / (float)B_TOTAL;
    float var   = qq / (float)B_TOTAL - mean * mean;
    float scale = g_[t] / sqrtf(var + 1e-5f);
    ws_out[8192 + t]      = scale;
    ws_out[8192 + 16 + t] = b_[t] - mean * scale;
  }
}

// ---------------- Weight packing: f32 -> bf16 in MFMA fragment order ---------
__global__ __launch_bounds__(256) void pack_weights(const float* __restrict__ W1,
                                                    const float* __restrict__ W2,
                                                    const float* __restrict__ Wl,
                                                    ushort_t* __restrict__ w1p,
                                                    ushort_t* __restrict__ w2p,
                                                    ushort_t* __restrict__ wlp) {
  int u = blockIdx.x * 256 + threadIdx.x;
  if (u < 32768) {                                 // W1: K 48->64, N 512 (NT=32, KB=2)
    int i = u & 7, lane = (u >> 3) & 63, kb = u >> 14;
    int k = kb * 32 + ((lane >> 4) << 3) + i;
    int n = (((u >> 9) & 31) << 4) + (lane & 15);
    w1p[u] = f2bf(k < 48 ? W1[k * 512 + n] : 0.f);
  } else if (u < 32768 + 131072) {                 // W2: K 512, N 256 (NT=16, KB=16)
    int v = u - 32768;
    int i = v & 7, lane = (v >> 3) & 63, kb = v >> 13;
    int k = kb * 32 + ((lane >> 4) << 3) + i;
    int n = (((v >> 9) & 15) << 4) + (lane & 15);
    w2p[v] = f2bf(W2[k * 256 + n]);
  } else if (u < 32768 + 131072 + 12288) {         // Wlin: K 384 (ffc 0..107 pad->128 | h2 128..383), N 24->32
    int v = u - (32768 + 131072);
    int i = v & 7, lane = (v >> 3) & 63, kb = v >> 10;
    int k = kb * 32 + ((lane >> 4) << 3) + i;
    int n = (((v >> 9) & 1) << 4) + (lane & 15);
    float val = 0.f;
    if (n < 24) {
      if (k < 108)       val = Wl[k * 24 + n];
      else if (k >= 128) val = Wl[(k - 20) * 24 + n];
    }
    wlp[v] = f2bf(val);
  }
}

// ---------------- Conv-as-GEMM weight matrices -------------------------------
struct WkPtrs { const float* wk[12]; };

__global__ __launch_bounds__(256) void pack_conv(WkPtrs wp,
                                                 ushort_t* __restrict__ Apack,
                                                 ushort_t* __restrict__ Bpack) {
  int u = blockIdx.x * 256 + threadIdx.x;
  if (u < 20480) {
    int i = u & 7, lane = (u >> 3) & 63;
    int knt = u >> 9;                  // kb*5 + nt
    int kb = knt / 5, nt = knt % 5;
    int k = kb * 32 + ((lane >> 4) << 3) + i;
    int n = nt * 16 + (lane & 15);
    float val = 0.f;
    if (n < 72 && k < 240) {
      int br = n / 12, ii = n - br * 12, ks = br + 1, lin = 240 - br;
      int si = ii * lin / 12, ei = ((ii + 1) * lin + 11) / 12;
      const float* wa = wp.wk[2 * br];
      float acc = 0.f;
      for (int kk = 0; kk < ks; ++kk) {
        int j = k - kk;
        if (j >= si && j < ei) acc += wa[kk];
      }
      val = acc / (float)(ei - si);
    }
    Apack[u] = f2bf(val);
  } else if (u < 20480 + 6144) {
    int v = u - 20480;
    int i = v & 7, lane = (v >> 3) & 63;
    int knt = v >> 9;                  // kb*3 + nt
    int kb = knt / 3, nt = knt % 3;
    int kcol = kb * 32 + ((lane >> 4) << 3) + i;
    int n = nt * 16 + (lane & 15);
    float val = 0.f;
    if (n < 36 && kcol < 108) {
      int brk = kcol / 18, ii = kcol - brk * 18;
      int brn = n / 6, j = n - brn * 6;
      if (brk == brn && ii < 12) {
        int ks = brn + 1, lcb = 12 - 2 * brn;
        int sj = j * lcb / 6, ej = ((j + 1) * lcb + 5) / 6;
        const float* wb = wp.wk[2 * brn + 1];
        float acc = 0.f;
        for (int kk = 0; kk < ks; ++kk) {
          int q = ii - 2 * kk;
          if (q >= sj && q < ej) acc += wb[kk];
        }
        val = acc / (float)(ej - sj);
      }
    }
    Bpack[v] = f2bf(val);
  }
}

// ---------------- Fully fused kernel: 32 samples / block ---------------------
struct FusedParams {
  const float* xw;
  const int*   xcat;
  const float* xcont;
  const float* E0; const float* E1; const float* E2;
  const float* b1; const float* b2;
  const ushort_t* Apack; const ushort_t* Bpack;
  const ushort_t* w1p; const ushort_t* w2p; const ushort_t* wlp;
  const float* stats;
  float*       out;
};

__global__ __launch_bounds__(512, 6) void fused_kernel(FusedParams p) {
  // LDS 44 KB -> 3 blocks/CU. Region 0 overlays three lifetimes:
  //   [0,16K)  s_xw bf16[32][256] swz rb=512   (conv input)
  //   [0,32K)  s_h1 bf16[32][512] swz rb=1024  (GEMM1 out; overwrites xw)
  //   [0,16K)  s_h2 bf16[32][256] swz rb=512   (GEMM2 out; overwrites h1)
  //   [32K,40K) s_cf bf16[32][128] swz rb=256  (conv feats; persists to GEMM3)
  //   [40K,44K) s_x48 bf16[32][64] swz rb=128
  __shared__ __align__(16) char smem[45056];
  ushort_t* s_xw  = (ushort_t*)smem;
  ushort_t* s_h1  = (ushort_t*)smem;
  ushort_t* s_h2  = (ushort_t*)smem;
  ushort_t* s_cf  = (ushort_t*)(smem + 32768);
  ushort_t* s_x48 = (ushort_t*)(smem + 40960);

  const int t    = threadIdx.x;
  const int lane = t & 63;
  const int w    = t >> 6;
  const int s0   = blockIdx.x * 32;
  const f32x4 fzero = {0.f, 0.f, 0.f, 0.f};

  // ---- Stage phase: zero s_cf, pad xw cols 240..255, stage xw, build x48
  ((uint4*)s_cf)[t] = uint4{0, 0, 0, 0};                       // 512 x 16B = 8KB
  if (t < 64) {
    int r = t >> 1, m = t & 1;
    *(uint4*)((char*)s_xw + ((r * 512 + 480 + m * 16) ^ ((r & 7) << 4))) = uint4{0, 0, 0, 0};
  }
  for (int u = t; u < 32 * 60; u += 512) {
    int s = u / 60, m4 = u - s * 60;
    float4 v = *(const float4*)(p.xw + (size_t)(s0 + s) * 240 + 4 * m4);
    uint2 pkv; pkv.x = pk2(v.x, v.y); pkv.y = pk2(v.z, v.w);
    *(uint2*)((char*)s_xw + ((s * 512 + m4 * 8) ^ ((s & 7) << 4))) = pkv;
  }
  if (t < 512) { int s = t >> 4; s_x48[swzi(s, 128, 48 + (t & 15))] = 0; }
  for (int u = t; u < 32 * 48; u += 512) {
    int s = u / 48, c = u - s * 48, gs = s0 + s;
    float v;
    if (c < 20)      v = p.E0[(size_t)p.xcat[gs * 3 + 0] * 20 + c];
    else if (c < 24) v = p.E1[(size_t)p.xcat[gs * 3 + 1] * 4 + (c - 20)];
    else if (c < 32) v = p.E2[(size_t)p.xcat[gs * 3 + 2] * 8 + (c - 24)];
    else { int cc = c - 32; v = p.xcont[(size_t)gs * 16 + cc] * p.stats[cc] + p.stats[16 + cc]; }
    s_x48[swzi(s, 128, c)] = f2bf(v);
  }
  __syncthreads();   // ---- A

  // ---- Phase 1: GEMM0a  FA[72 n][32 samp] = leaky(xw @ A) -> s_cf cols n+6*br
  auto do0a = [&](int nt, int st) {
    f32x4 acc = fzero;
    #pragma unroll
    for (int kb = 0; kb < 8; ++kb) {
      bf16x8 a = ld_frag(p.Apack + (size_t)((kb * 5 + nt) * 64 + lane) * 8);
      bf16x8 b = frag_swz(s_xw, st * 16 + (lane & 15), 512, kb * 32 + ((lane >> 4) << 3));
      acc = mfma16(a, b, acc);
    }
    int n0 = nt * 16 + ((lane >> 4) << 2);
    int br = n0 / 12;                 // pad n>=72 -> col 108..115 (stays zero)
    int col0 = n0 + 6 * br;
    int row = st * 16 + (lane & 15);
    unsigned lo = pk2(lrelu(acc[0]), lrelu(acc[1]));
    unsigned hi = pk2(lrelu(acc[2]), lrelu(acc[3]));
    *(unsigned*)((char*)s_cf + ((row * 256 + col0 * 2) ^ ((row & 7) << 4))) = lo;
    *(unsigned*)((char*)s_cf + ((row * 256 + (col0 + 2) * 2) ^ ((row & 7) << 4))) = hi;
  };
  do0a(w % 5, w / 5);               // 10 tiles (5 nt x 2 st) over 8 waves
  if (w < 2) do0a(w + 3, 1);
  __syncthreads();   // ---- B

  // ---- Phase 2: W2 prefetch + GEMM0b accumulate + GEMM1 (h1 overwrites xw)
  const int nt2 = w * 2;
  uint4 pa[2][2];
  #pragma unroll
  for (int q = 0; q < 2; ++q) {
    pa[q][0] = *(const uint4*)(p.w2p + (size_t)((q * 16 + nt2 + 0) * 64 + lane) * 8);
    pa[q][1] = *(const uint4*)(p.w2p + (size_t)((q * 16 + nt2 + 1) * 64 + lane) * 8);
  }

  const int ntB = w % 3, stB = w / 3;     // GEMM0b: 6 tiles, waves 0..5
  f32x4 accB = fzero;
  if (w < 6) {
    #pragma unroll
    for (int kb = 0; kb < 4; ++kb) {
      bf16x8 a = ld_frag(p.Bpack + (size_t)((kb * 3 + ntB) * 64 + lane) * 8);
      bf16x8 b = frag_swz(s_cf, stB * 16 + (lane & 15), 256, kb * 32 + ((lane >> 4) << 3));
      accB = mfma16(a, b, accB);
    }
  }

  {  // GEMM1: h1[512 n][32 samp] = relu(x48 @ W1 + b1); wave w: nt = 4w..4w+3
    bf16x8 bx[2][2];
    #pragma unroll
    for (int st = 0; st < 2; ++st)
      #pragma unroll
      for (int kb = 0; kb < 2; ++kb)
        bx[st][kb] = frag_swz(s_x48, st * 16 + (lane & 15), 128, kb * 32 + ((lane >> 4) << 3));
    #pragma unroll
    for (int j = 0; j < 4; ++j) {
      int nt = w * 4 + j;
      bf16x8 a0 = ld_frag(p.w1p + (size_t)((0 * 32 + nt) * 64 + lane) * 8);
      bf16x8 a1 = ld_frag(p.w1p + (size_t)((1 * 32 + nt) * 64 + lane) * 8);
      f32x4 acc[2];
      #pragma unroll
      for (int st = 0; st < 2; ++st) {
        acc[st] = mfma16(a0, bx[st][0], fzero);
        acc[st] = mfma16(a1, bx[st][1], acc[st]);
      }
      int n0 = nt * 16 + ((lane >> 4) << 2);
      float4 bb = *(const float4*)(p.b1 + n0);
      #pragma unroll
      for (int st = 0; st < 2; ++st) {
        int row = st * 16 + (lane & 15);
        float v0 = fmaxf(acc[st][0] + bb.x, 0.f);
        float v1 = fmaxf(acc[st][1] + bb.y, 0.f);
        float v2 = fmaxf(acc[st][2] + bb.z, 0.f);
        float v3 = fmaxf(acc[st][3] + bb.w, 0.f);
        uint2 pkv; pkv.x = pk2(v0, v1); pkv.y = pk2(v2, v3);
        *(uint2*)((char*)s_h1 + ((row * 1024 + n0 * 2) ^ ((row & 7) << 4))) = pkv;
      }
    }
  }
  __syncthreads();   // ---- C

  // ---- Phase 3: write fb into s_cf + GEMM2 accumulate (no barriers inside)
  if (w < 6) {   // fb: n = br*6+j -> col = n + 12*(br+1)
    int n0 = ntB * 16 + ((lane >> 4) << 2);
    if (n0 < 36) {
      int row = stB * 16 + (lane & 15);
      int br0 = n0 / 6, c0 = n0 + 12 * (br0 + 1);
      int n2 = n0 + 2, br2 = n2 / 6, c2 = n2 + 12 * (br2 + 1);
      *(unsigned*)((char*)s_cf + ((row * 256 + c0 * 2) ^ ((row & 7) << 4))) =
          pk2(lrelu(accB[0]), lrelu(accB[1]));
      *(unsigned*)((char*)s_cf + ((row * 256 + c2 * 2) ^ ((row & 7) << 4))) =
          pk2(lrelu(accB[2]), lrelu(accB[3]));
    }
  }

  f32x4 acc2[2][2];
  #pragma unroll
  for (int jm = 0; jm < 2; ++jm) { acc2[jm][0] = fzero; acc2[jm][1] = fzero; }
  #pragma unroll
  for (int kb = 0; kb < 16; ++kb) {
    bf16x8 a0 = __builtin_bit_cast(bf16x8, pa[kb & 1][0]);
    bf16x8 a1 = __builtin_bit_cast(bf16x8, pa[kb & 1][1]);
    if (kb < 14) {
      pa[kb & 1][0] = *(const uint4*)(p.w2p + (size_t)(((kb + 2) * 16 + nt2 + 0) * 64 + lane) * 8);
      pa[kb & 1][1] = *(const uint4*)(p.w2p + (size_t)(((kb + 2) * 16 + nt2 + 1) * 64 + lane) * 8);
    }
    #pragma unroll
    for (int st = 0; st < 2; ++st) {
      bf16x8 b = frag_swz(s_h1, st * 16 + (lane & 15), 1024, kb * 32 + ((lane >> 4) << 3));
      acc2[0][st] = mfma16(a0, b, acc2[0][st]);
      acc2[1][st] = mfma16(a1, b, acc2[1][st]);
    }
  }
  __syncthreads();   // ---- D  (all h1 reads complete)

  // ---- Phase 4: h2 epilogue -> s_h2 [32][256] rb=512
  #pragma unroll
  for (int jm = 0; jm < 2; ++jm) {
    int n0 = (nt2 + jm) * 16 + ((lane >> 4) << 2);
    float4 bb = *(const float4*)(p.b2 + n0);
    #pragma unroll
    for (int st = 0; st < 2; ++st) {
      int row = st * 16 + (lane & 15);
      float v0 = fmaxf(acc2[jm][st][0] + bb.x, 0.f);
      float v1 = fmaxf(acc2[jm][st][1] + bb.y, 0.f);
      float v2 = fmaxf(acc2[jm][st][2] + bb.z, 0.f);
      float v3 = fmaxf(acc2[jm][st][3] + bb.w, 0.f);
      uint2 pkv; pkv.x = pk2(v0, v1); pkv.y = pk2(v2, v3);
      *(uint2*)((char*)s_h2 + ((row * 512 + n0 * 2) ^ ((row & 7) << 4))) = pkv;
    }
  }
  __syncthreads();   // ---- E

  // ---- Phase 5: GEMM3  out[32][24] = [cf(128) | h2(256)] @ Wlin ; waves 0-3
  if (w < 4) {
    const int st = w & 1, nt = w >> 1;
    f32x4 acc = fzero;
    #pragma unroll
    for (int kb = 0; kb < 12; ++kb) {
      bf16x8 a = ld_frag(p.wlp + (size_t)((kb * 2 + nt) * 64 + lane) * 8);
      bf16x8 b;
      if (kb < 4) b = frag_swz(s_cf, st * 16 + (lane & 15), 256, kb * 32 + ((lane >> 4) << 3));
      else        b = frag_swz(s_h2, st * 16 + (lane & 15), 512, (kb - 4) * 32 + ((lane >> 4) << 3));
      acc = mfma16(a, b, acc);
    }
    int n0 = nt * 16 + ((lane >> 4) << 2);
    if (n0 < 24) {
      int sg = s0 + st * 16 + (lane & 15);
      *(float2*)(p.out + (size_t)sg * 24 + n0)     = make_float2(acc[0], acc[1]);
      *(float2*)(p.out + (size_t)sg * 24 + n0 + 2) = make_float2(acc[2], acc[3]);
    }
  }
}

// ---------------- launch -----------------------------------------------------
extern "C" void kernel_launch(void* const* d_in, const int* in_sizes, int n_in,
                              void* d_out, int out_size, void* d_ws, size_t ws_size,
                              hipStream_t stream) {
  const float* xcont = (const float*)d_in[2];
  float* ws  = (float*)d_ws;
  char*  wsb = (char*)d_ws;
  ushort_t* w1p   = (ushort_t*)(wsb + 36864);    //  64 KB
  ushort_t* w2p   = (ushort_t*)(wsb + 102400);   // 256 KB
  ushort_t* wlp   = (ushort_t*)(wsb + 364544);   //  24 KB
  ushort_t* Apack = (ushort_t*)(wsb + 389120);   //  40 KB
  ushort_t* Bpack = (ushort_t*)(wsb + 430080);   //  12 KB

  WkPtrs wp;
  for (int i = 0; i < 12; ++i) wp.wk[i] = (const float*)d_in[3 + i];
  pack_conv<<<104, 256, 0, stream>>>(wp, Apack, Bpack);
  bn_partial<<<256, 256, 0, stream>>>(xcont, ws);
  bn_final<<<1, 256, 0, stream>>>(ws, ws, (const float*)d_in[18], (const float*)d_in[19]);
  pack_weights<<<688, 256, 0, stream>>>((const float*)d_in[20], (const float*)d_in[22],
                                        (const float*)d_in[24], w1p, w2p, wlp);

  FusedParams p;
  p.xw    = (const float*)d_in[0];
  p.xcat  = (const int*)d_in[1];
  p.xcont = xcont;
  p.E0 = (const float*)d_in[15]; p.E1 = (const float*)d_in[16]; p.E2 = (const float*)d_in[17];
  p.b1 = (const float*)d_in[21]; p.b2 = (const float*)d_in[23];
  p.Apack = Apack; p.Bpack = Bpack;
  p.w1p = w1p; p.w2p = w2p; p.wlp = wlp;
  p.stats = ws + 8192;
  p.out = (float*)d_out;
  fused_kernel<<<B_TOTAL / 32, 512, 0, stream>>>(p);
}